// Round 7
// baseline (409.370 us; speedup 1.0000x reference)
//
#include <hip/hip_runtime.h>
#include <cstdint>
#include <math.h>

#define NB 128  // batch size

// ---------------------------------------------------------------------------
// Weight packing.
// Layers 2-6: layout wp[ocg][tap][cw][oc64]  (oc64 = lane) so a wave's 64
//   weight words per (tap,cw) are one coalesced dword load.
// Layer 7:    layout wp[o][tap][cw] (conv7 consumes linearly).
// Layer 1:    wp1[(ocg*27+t)*2+half] : 64-bit sign mask per (ocg,tap).
// bit (c%32) of word = (w[o][c][kh][kw] >= 0)
// ---------------------------------------------------------------------------
__global__ void pack_all_kernel(
    const float* __restrict__ w1,
    const float* __restrict__ w2, const float* __restrict__ w3,
    const float* __restrict__ w4, const float* __restrict__ w5,
    const float* __restrict__ w6, const float* __restrict__ w7,
    uint32_t* __restrict__ wp1,
    uint32_t* __restrict__ wp2, uint32_t* __restrict__ wp3,
    uint32_t* __restrict__ wp4, uint32_t* __restrict__ wp5,
    uint32_t* __restrict__ wp6, uint32_t* __restrict__ wp7) {
  int i = blockIdx.x * 256 + threadIdx.x;
  if (i >= 145516) return;
  if (i >= 145408) {  // conv1 sign masks
    int j = i - 145408;          // 0..107
    int ocg = j / 54, rem = j % 54, t = rem >> 1, half = rem & 1;
    uint32_t word = 0;
    for (int b = 0; b < 32; ++b)
      word |= ((w1[(ocg * 64 + half * 32 + b) * 27 + t] >= 0.0f) ? 1u : 0u) << b;
    wp1[(ocg * 27 + t) * 2 + half] = word;
    return;
  }
  const float* w; uint32_t* wp; int C, KHW; bool nl = true;
  if (i < 4608)        { w = w2; wp = wp2; C = 128; KHW = 9; }
  else if (i < 13824)  { i -= 4608;   w = w3; wp = wp3; C = 128; KHW = 9; }
  else if (i < 32256)  { i -= 13824;  w = w4; wp = wp4; C = 256; KHW = 9; }
  else if (i < 69120)  { i -= 32256;  w = w5; wp = wp5; C = 256; KHW = 9; }
  else if (i < 142848) { i -= 69120;  w = w6; wp = wp6; C = 512; KHW = 9; }
  else                 { i -= 142848; w = w7; wp = wp7; C = 512; KHW = 16; nl = false; }
  int Cw = C >> 5;
  int cw = i % Cw;
  int rest = i / Cw;
  int t = rest % KHW;
  int o = rest / KHW;
  uint32_t word = 0;
  for (int b = 0; b < 32; ++b)
    word |= ((w[(o * C + cw * 32 + b) * KHW + t] >= 0.0f) ? 1u : 0u) << b;
  if (nl) wp[(((o >> 6) * KHW + t) * Cw + cw) * 64 + (o & 63)] = word;
  else    wp[(o * KHW + t) * Cw + cw] = word;
}

// per-lane select from a wave-uniform 64-bit mask (lowers to mask-as-VCC)
__device__ __forceinline__ bool lane_bit(uint64_t m, int lane) {
#if __has_builtin(__builtin_amdgcn_inverse_ballot_w64)
  (void)lane;
  return __builtin_amdgcn_inverse_ballot_w64(m);
#else
  return (m >> lane) & 1;
#endif
}

// A zero the compiler must treat as divergent: forces act loads onto the
// VMEM path (uniform-address per-lane loads broadcast from L1) instead of
// the scalar pipe, which serializes under streaming (one scalar unit/CU).
__device__ __forceinline__ int v_zero() {
  return __builtin_amdgcn_ds_bpermute(0, 0);
}

// ---------------------------------------------------------------------------
// Conv1, oc-in-lane weight-stationary. lane = oc in ocg (blockIdx.y of 2),
// wave covers R rows x PC cols of one image.
// Fast path: per-lane sgn[27] in {+-1.0f}; inner MAC = one v_fmac_f32 with a
//   broadcast activation; accabs tracks sum|x| per pixel.
// Exactness: f32 summation error <= gamma_26 * sum|x| = 1.55e-6 * accabs.
//   Decisions with |s*acc+t| >= 2e-6*accabs*s are provably identical to the
//   f64 reference; flagged lanes (~100 per 16.7M) recompute exactly in f64.
// Epilogue: __ballot packs 64 sign bits -> one 8B store per pixel.
// ---------------------------------------------------------------------------
template <int PC, int R>
__global__ __launch_bounds__(64, 2) void conv1_kernel(
    const float* __restrict__ x, const uint32_t* __restrict__ wp1,
    const float* __restrict__ bs, const float* __restrict__ bt,
    uint32_t* __restrict__ out) {
  const int lane = threadIdx.x;
  const int ocg = blockIdx.y;
  const int zero = v_zero();
  const int cpr = 32 / PC;
  const int c = blockIdx.x;
  const int cg = c % cpr;
  const int rg = (c / cpr) % (32 / R);
  const int n  = c / (cpr * (32 / R));
  const int y0 = rg * R, x0 = cg * PC;

  const uint64_t* wm64 = (const uint64_t*)wp1;
  float sgn[27];
#pragma unroll
  for (int t = 0; t < 27; ++t)
    sgn[t] = lane_bit(wm64[ocg * 27 + t], lane) ? 1.0f : -1.0f;

  float acc[R * PC], accabs[R * PC];
#pragma unroll
  for (int p = 0; p < R * PC; ++p) { acc[p] = 0.0f; accabs[p] = 0.0f; }

#pragma unroll
  for (int ic = 0; ic < 3; ++ic) {
#pragma unroll
    for (int ey = -1; ey <= R; ++ey) {
      const int y = y0 + ey;
      if (y < 0 || y >= 32) continue;          // uniform branch
#pragma unroll
      for (int ex = -1; ex <= PC; ++ex) {
        const int xx = x0 + ex;
        if (xx < 0 || xx >= 32) continue;      // uniform branch
        const float xv = x[zero + ((n * 3 + ic) * 32 + y) * 32 + xx];  // VMEM bcast
        const float xa = fabsf(xv);
#pragma unroll
        for (int r = 0; r < R; ++r) {
          const int kh = ey - r + 1;           // compile-time after unroll
          if (kh < 0 || kh > 2) continue;
#pragma unroll
          for (int kw = 0; kw < 3; ++kw) {
            const int pxo = ex - kw + 1;       // compile-time
            if (pxo < 0 || pxo >= PC) continue;
            acc[r * PC + pxo] = fmaf(xv, sgn[ic * 9 + kh * 3 + kw], acc[r * PC + pxo]);
            accabs[r * PC + pxo] += xa;
          }
        }
      }
    }
  }

  const double sd = (double)bs[ocg * 64 + lane];
  const double td = (double)bt[ocg * 64 + lane];
  uint64_t bal[R * PC];
#pragma unroll
  for (int r = 0; r < R; ++r)
#pragma unroll
    for (int pxo = 0; pxo < PC; ++pxo) {
      double v = (double)acc[r * PC + pxo] * sd + td;
      const bool risky = fabs(v) < (double)(2.0e-6f * accabs[r * PC + pxo]) * sd;
      if (__any(risky)) {                      // ~never
        if (risky) {                           // exact f64 recompute
          const int y = y0 + r, xp = x0 + pxo;
          double ad = 0.0;
          for (int ic = 0; ic < 3; ++ic)
            for (int kh = 0; kh < 3; ++kh) {
              const int yy = y + kh - 1;
              if ((unsigned)yy >= 32u) continue;
              for (int kw = 0; kw < 3; ++kw) {
                const int xc = xp + kw - 1;
                if ((unsigned)xc >= 32u) continue;
                const double xd = (double)x[((n * 3 + ic) * 32 + yy) * 32 + xc];
                ad += (sgn[ic * 9 + kh * 3 + kw] > 0.0f) ? xd : -xd;
              }
            }
          v = ad * sd + td;
        }
      }
      bal[r * PC + pxo] = __ballot(v >= 0.0);
    }
  if (lane == 0) {
#pragma unroll
    for (int r = 0; r < R; ++r)
#pragma unroll
      for (int pxo = 0; pxo < PC; ++pxo) {
        const int p = ((n * 32 + (y0 + r)) * 32 + (x0 + pxo));
        *(uint64_t*)(out + p * 4 + ocg * 2) = bal[r * PC + pxo];
      }
  }
}

// ---------------------------------------------------------------------------
// Binary conv 3x3 pad=1 — oc-in-lane, weight-stationary.
//   lane = oc in the wave's 64-oc group (blockIdx.y); 1 wave = R x PC pixels.
// Weights: 9*CWP lane-private VGPRs per pass. Acts: VMEM broadcast loads
//   (uniform address + divergent zero -> global_load, 63 outstanding, L1
//   broadcast) — NOT the scalar pipe. Inner op: v_xor + accumulating v_bcnt.
// Border taps: uniform branches. Epilogue: bn sign in f64 (exact);
//   __ballot packs 64 sign bits -> one 8B store. POOL: OR of 2x2 ballots.
// ---------------------------------------------------------------------------
template <int CW, int CWP, int H, int W, int PC, int R, bool POOL>
__global__ __launch_bounds__(64, 2) void bconv_kernel(
    const uint32_t* __restrict__ act, const uint32_t* __restrict__ wpk,
    const float* __restrict__ bs, const float* __restrict__ bt,
    uint32_t* __restrict__ out, int OCW) {
  static_assert(CW % CWP == 0, "");
  const int lane = threadIdx.x;
  const int ocg = blockIdx.y;
  const int zero = v_zero();
  const int cpr = W / PC;
  const int c = blockIdx.x;
  const int cg = c % cpr;
  const int rg = (c / cpr) % (H / R);
  const int n  = c / (cpr * (H / R));
  const int y0 = rg * R, x0 = cg * PC;

  int acc[R * PC];
#pragma unroll
  for (int p = 0; p < R * PC; ++p) acc[p] = 0;

#pragma unroll
  for (int pass = 0; pass < CW / CWP; ++pass) {
    uint32_t wreg[9 * CWP];
#pragma unroll
    for (int t = 0; t < 9; ++t)
#pragma unroll
      for (int cw = 0; cw < CWP; ++cw)
        wreg[t * CWP + cw] = wpk[(((ocg * 9) + t) * CW + pass * CWP + cw) * 64 + lane];

#pragma unroll
    for (int ry = -1; ry <= R; ++ry) {
      const int y = y0 + ry;
      if (y < 0 || y >= H) continue;          // uniform branch
#pragma unroll
      for (int cc = -1; cc <= PC; ++cc) {
        const int x = x0 + cc;
        if (x < 0 || x >= W) continue;        // uniform branch
        const uint32_t* ap = act + zero + ((n * H + y) * W + x) * CW + pass * CWP;
        uint32_t av[CWP];
#pragma unroll
        for (int cw = 0; cw < CWP; ++cw) av[cw] = ap[cw];  // VMEM bcast dwordx4
#pragma unroll
        for (int r = 0; r < R; ++r) {
          const int kh = ry - r + 1;          // compile-time after unroll
          if (kh < 0 || kh > 2) continue;
#pragma unroll
          for (int kw = 0; kw < 3; ++kw) {
            const int pxo = cc - kw + 1;      // compile-time
            if (pxo < 0 || pxo >= PC) continue;
#pragma unroll
            for (int cw = 0; cw < CWP; ++cw)
              acc[r * PC + pxo] += __popc(av[cw] ^ wreg[(kh * 3 + kw) * CWP + cw]);
          }
        }
      }
    }
  }

  const double sd = (double)bs[ocg * 64 + lane];
  const double td = (double)bt[ocg * 64 + lane];
  if (!POOL) {
    uint64_t bal[R * PC];
#pragma unroll
    for (int r = 0; r < R; ++r)
#pragma unroll
      for (int pxo = 0; pxo < PC; ++pxo) {
        const int y = y0 + r, x = x0 + pxo;
        const int nv = CW * (3 - (y == 0) - (y == H - 1)) * (3 - (x == 0) - (x == W - 1));
        double v = (double)(32 * nv - 2 * acc[r * PC + pxo]) * sd + td;
        bal[r * PC + pxo] = __ballot(v >= 0.0);
      }
    if (lane == 0) {
#pragma unroll
      for (int r = 0; r < R; ++r)
#pragma unroll
        for (int pxo = 0; pxo < PC; ++pxo)
          *(uint64_t*)(out + ((n * H + (y0 + r)) * W + (x0 + pxo)) * OCW + ocg * 2) =
              bal[r * PC + pxo];
    }
  } else {
    static_assert(!POOL || R == 2, "pool needs row pairs");
    uint64_t pooled[PC / 2];
#pragma unroll
    for (int c2 = 0; c2 < PC / 2; ++c2) pooled[c2] = 0;
#pragma unroll
    for (int r = 0; r < R; ++r)
#pragma unroll
      for (int pxo = 0; pxo < PC; ++pxo) {
        const int y = y0 + r, x = x0 + pxo;
        const int nv = CW * (3 - (y == 0) - (y == H - 1)) * (3 - (x == 0) - (x == W - 1));
        double v = (double)(32 * nv - 2 * acc[r * PC + pxo]) * sd + td;
        pooled[pxo >> 1] |= __ballot(v >= 0.0);
      }
    if (lane == 0) {
#pragma unroll
      for (int c2 = 0; c2 < PC / 2; ++c2) {
        const int yo = y0 >> 1, xo = (x0 >> 1) + c2;
        *(uint64_t*)(out + ((n * (H / 2) + yo) * (W / 2) + xo) * OCW + ocg * 2) =
            pooled[c2];
      }
    }
  }
}

// ---------------------------------------------------------------------------
// Conv7 (4x4 VALID, K=512*16=8192 = 256 words) + bn7 + log_softmax (double)
// One block (1 wave) per image.
// ---------------------------------------------------------------------------
__global__ __launch_bounds__(64) void conv7_kernel(
    const uint32_t* __restrict__ act, const uint32_t* __restrict__ wp,
    const float* __restrict__ bs, const float* __restrict__ bt,
    float* __restrict__ out) {
  int n = blockIdx.x;
  int lane = threadIdx.x;
  const uint32_t* a = act + n * 256;
  __shared__ double logits[10];
  for (int o = 0; o < 10; ++o) {
    int acc = 0;
    for (int w = lane; w < 256; w += 64) acc += __popc(a[w] ^ wp[o * 256 + w]);
    for (int off = 32; off > 0; off >>= 1) acc += __shfl_down(acc, off, 64);
    if (lane == 0) {
      double dotd = (double)(8192 - 2 * acc);
      logits[o] = dotd * (double)bs[o] + (double)bt[o];
    }
  }
  __syncthreads();
  if (lane == 0) {
    double m = logits[0];
    for (int o = 1; o < 10; ++o) m = fmax(m, logits[o]);
    double s = 0.0;
    for (int o = 0; o < 10; ++o) s += exp(logits[o] - m);
    double lse = log(s);
    for (int o = 0; o < 10; ++o) out[n * 10 + o] = (float)(logits[o] - m - lse);
  }
}

// ---------------------------------------------------------------------------
extern "C" void kernel_launch(void* const* d_in, const int* in_sizes, int n_in,
                              void* d_out, int out_size, void* d_ws, size_t ws_size,
                              hipStream_t stream) {
  const float* x  = (const float*)d_in[0];
  const float* w1 = (const float*)d_in[1];
  const float* w2 = (const float*)d_in[2];
  const float* w3 = (const float*)d_in[3];
  const float* w4 = (const float*)d_in[4];
  const float* w5 = (const float*)d_in[5];
  const float* w6 = (const float*)d_in[6];
  const float* w7 = (const float*)d_in[7];
  const float* s1 = (const float*)d_in[8];  const float* t1 = (const float*)d_in[9];
  const float* s2 = (const float*)d_in[10]; const float* t2 = (const float*)d_in[11];
  const float* s3 = (const float*)d_in[12]; const float* t3 = (const float*)d_in[13];
  const float* s4 = (const float*)d_in[14]; const float* t4 = (const float*)d_in[15];
  const float* s5 = (const float*)d_in[16]; const float* t5 = (const float*)d_in[17];
  const float* s6 = (const float*)d_in[18]; const float* t6 = (const float*)d_in[19];
  const float* s7 = (const float*)d_in[20]; const float* t7 = (const float*)d_in[21];
  float* out = (float*)d_out;

  uint32_t* ws = (uint32_t*)d_ws;
  uint32_t* A   = ws;                 // 524288 words (2 MB) ping
  uint32_t* B   = ws + 524288;        // 524288 words pong
  uint32_t* wp2 = ws + 1048576;       // 2*9*4*64   = 4608
  uint32_t* wp3 = wp2 + 4608;         // 4*9*4*64   = 9216
  uint32_t* wp4 = wp3 + 9216;         // 4*9*8*64   = 18432
  uint32_t* wp5 = wp4 + 18432;        // 8*9*8*64   = 36864
  uint32_t* wp6 = wp5 + 36864;        // 8*9*16*64  = 73728
  uint32_t* wp7 = wp6 + 73728;        // 10*16*16   = 2560
  uint32_t* wp1 = wp7 + 2560;         // 2*27*2     = 108   (8B-aligned)

  // pack all weights in one dispatch (ws re-poisoned every call -> repack)
  pack_all_kernel<<<dim3(569), dim3(256), 0, stream>>>(
      w1, w2, w3, w4, w5, w6, w7, wp1, wp2, wp3, wp4, wp5, wp6, wp7);

  // L1: conv1 (f32 fmac + sound-threshold f64 fixup) -> A [128,32,32,4]
  conv1_kernel<4, 2><<<dim3(16384, 2), dim3(64), 0, stream>>>(x, wp1, s1, t1, A);

  // L2: bconv+pool (CW=4, 32x32) A->B [128,16,16,4]
  bconv_kernel<4, 4, 32, 32, 8, 2, true>
      <<<dim3(8192, 2), dim3(64), 0, stream>>>(A, wp2, s2, t2, B, 4);

  // L3: bconv (CW=4, 16x16, OC=256) B->A [128,16,16,8]
  bconv_kernel<4, 4, 16, 16, 8, 1, false>
      <<<dim3(4096, 4), dim3(64), 0, stream>>>(B, wp3, s3, t3, A, 8);

  // L4: bconv+pool (CW=8 in 2 passes of 4) A->B [128,8,8,8]
  bconv_kernel<8, 4, 16, 16, 8, 2, true>
      <<<dim3(2048, 4), dim3(64), 0, stream>>>(A, wp4, s4, t4, B, 8);

  // L5: bconv (CW=8 in 2 passes of 4, 8x8, OC=512) B->A [128,8,8,16]
  bconv_kernel<8, 4, 8, 8, 8, 2, false>
      <<<dim3(512, 8), dim3(64), 0, stream>>>(B, wp5, s5, t5, A, 16);

  // L6: bconv+pool (CW=16 in 4 passes of 4) A->B [128,4,4,16]
  bconv_kernel<16, 4, 8, 8, 8, 2, true>
      <<<dim3(512, 8), dim3(64), 0, stream>>>(A, wp6, s6, t6, B, 16);

  // L7: conv7 + bn7 + log_softmax -> out [128,10]
  conv7_kernel<<<dim3(128), dim3(64), 0, stream>>>(B, wp7, s7, t7, out);
}

// Round 8
// 322.284 us; speedup vs baseline: 1.2702x; 1.2702x over previous
//
#include <hip/hip_runtime.h>
#include <cstdint>
#include <math.h>

#define NB 128  // batch size

// ---------------------------------------------------------------------------
// Weight packing.
// Layers 2-6: layout wp[ocg][tap][cw][oc64]  (oc64 = lane).
// Layer 7:    layout wp[o][tap][cw] (conv7 consumes linearly).
// Layer 1:    wp1[ocw*27 + t] : bit b = (w1[ocw*32+b][tap t] >= 0), ocw 0..3.
// bit (c%32) of word = (w[o][c][kh][kw] >= 0)
// ---------------------------------------------------------------------------
__global__ void pack_all_kernel(
    const float* __restrict__ w1,
    const float* __restrict__ w2, const float* __restrict__ w3,
    const float* __restrict__ w4, const float* __restrict__ w5,
    const float* __restrict__ w6, const float* __restrict__ w7,
    uint32_t* __restrict__ wp1,
    uint32_t* __restrict__ wp2, uint32_t* __restrict__ wp3,
    uint32_t* __restrict__ wp4, uint32_t* __restrict__ wp5,
    uint32_t* __restrict__ wp6, uint32_t* __restrict__ wp7) {
  int i = blockIdx.x * 256 + threadIdx.x;
  if (i >= 145516) return;
  if (i >= 145408) {  // conv1 sign masks
    int j = i - 145408;          // 0..107
    int ocw = j / 27, t = j % 27;
    uint32_t word = 0;
    for (int b = 0; b < 32; ++b)
      word |= ((w1[(ocw * 32 + b) * 27 + t] >= 0.0f) ? 1u : 0u) << b;
    wp1[ocw * 27 + t] = word;
    return;
  }
  const float* w; uint32_t* wp; int C, KHW; bool nl = true;
  if (i < 4608)        { w = w2; wp = wp2; C = 128; KHW = 9; }
  else if (i < 13824)  { i -= 4608;   w = w3; wp = wp3; C = 128; KHW = 9; }
  else if (i < 32256)  { i -= 13824;  w = w4; wp = wp4; C = 256; KHW = 9; }
  else if (i < 69120)  { i -= 32256;  w = w5; wp = wp5; C = 256; KHW = 9; }
  else if (i < 142848) { i -= 69120;  w = w6; wp = wp6; C = 512; KHW = 9; }
  else                 { i -= 142848; w = w7; wp = wp7; C = 512; KHW = 16; nl = false; }
  int Cw = C >> 5;
  int cw = i % Cw;
  int rest = i / Cw;
  int t = rest % KHW;
  int o = rest / KHW;
  uint32_t word = 0;
  for (int b = 0; b < 32; ++b)
    word |= ((w[(o * C + cw * 32 + b) * KHW + t] >= 0.0f) ? 1u : 0u) << b;
  if (nl) wp[(((o >> 6) * KHW + t) * Cw + cw) * 64 + (o & 63)] = word;
  else    wp[(o * KHW + t) * Cw + cw] = word;
}

// A zero the compiler must treat as divergent (used only in bconv base addr).
__device__ __forceinline__ int v_zero() {
  return __builtin_amdgcn_ds_bpermute(0, 0);
}

// ---------------------------------------------------------------------------
// Conv1 — pixel-per-lane. Each thread owns one pixel and 64 output chans
// (blockIdx.y picks the 64-oc group). The 27-tap fp32 window lives in VGPRs
// (coalesced loads, zero-padded via clamp+cndmask); weight signs are 27
// wave-uniform SGPR bitmasks; inner MAC = v_fmac_f32 with the +-1 selected
// on the scalar ALU (parallel pipe). Sign test in f32 with sound threshold
// 1e-3*s (f32 error <= gamma_27*sum|x| <= 2.4e-4, 4x margin; needs
// max|x|<23 — input is N(0,1)); flagged ocs recompute exactly in f64 from
// the register window (matches the f64 reference; downstream is chaotic in
// sign bits so decisions must be f64-exact). Output: one 8B store/thread.
// ---------------------------------------------------------------------------
__global__ __launch_bounds__(256, 2) void conv1_kernel(
    const float* __restrict__ x, const uint32_t* __restrict__ wp1,
    const float* __restrict__ bs, const float* __restrict__ bt,
    uint32_t* __restrict__ out) {
  const int tid = blockIdx.x * 256 + threadIdx.x;  // pixel id (exact grid)
  const int og = blockIdx.y;                       // 64-oc group
  const int px = tid & 31, py = (tid >> 5) & 31, n = tid >> 10;

  float xv[27];
#pragma unroll
  for (int ic = 0; ic < 3; ++ic)
#pragma unroll
    for (int kh = 0; kh < 3; ++kh) {
      const int yy = py + kh - 1;
      const int yc = min(max(yy, 0), 31);
      const float* row = x + ((n * 3 + ic) * 32 + yc) * 32;
#pragma unroll
      for (int kw = 0; kw < 3; ++kw) {
        const int xx = px + kw - 1;
        const int xc = min(max(xx, 0), 31);
        const float v = row[xc];
        const bool ok = ((unsigned)yy < 32u) && ((unsigned)xx < 32u);
        xv[ic * 9 + kh * 3 + kw] = ok ? v : 0.0f;
      }
    }

  uint32_t wout[2];
#pragma unroll
  for (int h = 0; h < 2; ++h) {
    const int ocw = og * 2 + h;
    uint32_t m[27];
#pragma unroll
    for (int t = 0; t < 27; ++t) m[t] = wp1[ocw * 27 + t];  // uniform -> SGPR
    uint32_t word = 0;
#pragma unroll
    for (int b = 0; b < 32; b += 4) {  // 4-way ILP on the fmac chains
      float a0 = 0.f, a1 = 0.f, a2 = 0.f, a3 = 0.f;
#pragma unroll
      for (int t = 0; t < 27; ++t) {
        const uint32_t mt = m[t];
        a0 = fmaf(xv[t], ((mt >> (b + 0)) & 1u) ? 1.0f : -1.0f, a0);
        a1 = fmaf(xv[t], ((mt >> (b + 1)) & 1u) ? 1.0f : -1.0f, a1);
        a2 = fmaf(xv[t], ((mt >> (b + 2)) & 1u) ? 1.0f : -1.0f, a2);
        a3 = fmaf(xv[t], ((mt >> (b + 3)) & 1u) ? 1.0f : -1.0f, a3);
      }
      float aa[4] = {a0, a1, a2, a3};
#pragma unroll
      for (int j = 0; j < 4; ++j) {
        const int oc = ocw * 32 + b + j;
        const float s = bs[oc], t0 = bt[oc];        // uniform scalars
        const float v = fmaf(aa[j], s, t0);
        bool pos = v >= 0.0f;
        if (fabsf(v) < 1e-3f * s) {                 // rare exact path
          double ad = 0.0;
          for (int t = 0; t < 27; ++t)
            ad += ((m[t] >> (b + j)) & 1u) ? (double)xv[t] : -(double)xv[t];
          pos = (ad * (double)s + (double)t0) >= 0.0;
        }
        word |= (pos ? 1u : 0u) << (b + j);
      }
    }
    wout[h] = word;
  }
  *(uint64_t*)(out + tid * 4 + og * 2) = ((uint64_t)wout[1] << 32) | wout[0];
}

// ---------------------------------------------------------------------------
// Binary conv 3x3 pad=1 — oc-in-lane, weight-stationary, ROW-BATCHED loads.
//   lane = oc in the wave's 64-oc group (blockIdx.y); 1 wave = R x PC pixels.
// Weights: 9*CWP lane-private VGPRs per pass. Acts: ONE base address per
//   row; all (PC+2) positions loaded as uint4 with compile-time immediate
//   offsets into a register buffer BEFORE the scatter-compute (independent
//   loads -> one waitcnt; no per-position address math).
// Inner op: v_xor + accumulating v_bcnt. Border rows/cols: uniform branches.
// Epilogue: bn sign in f64 (exact: s*dot has 24b x <=14b mantissas);
//   __ballot packs 64 sign bits -> one 8B store. POOL: OR of 2x2 ballots.
// ---------------------------------------------------------------------------
template <int CW, int CWP, int H, int W, int PC, int R, bool POOL>
__global__ __launch_bounds__(64, 2) void bconv_kernel(
    const uint32_t* __restrict__ act, const uint32_t* __restrict__ wpk,
    const float* __restrict__ bs, const float* __restrict__ bt,
    uint32_t* __restrict__ out, int OCW) {
  static_assert(CW % CWP == 0 && CWP % 4 == 0, "");
  const int lane = threadIdx.x;
  const int ocg = blockIdx.y;
  const int zero = v_zero();
  const int cpr = W / PC;
  const int c = blockIdx.x;
  const int cg = c % cpr;
  const int rg = (c / cpr) % (H / R);
  const int n  = c / (cpr * (H / R));
  const int y0 = rg * R, x0 = cg * PC;

  int acc[R * PC];
#pragma unroll
  for (int p = 0; p < R * PC; ++p) acc[p] = 0;

#pragma unroll
  for (int pass = 0; pass < CW / CWP; ++pass) {
    uint32_t wreg[9 * CWP];
#pragma unroll
    for (int t = 0; t < 9; ++t)
#pragma unroll
      for (int cw = 0; cw < CWP; ++cw)
        wreg[t * CWP + cw] = wpk[(((ocg * 9) + t) * CW + pass * CWP + cw) * 64 + lane];

#pragma unroll
    for (int ry = -1; ry <= R; ++ry) {
      const int y = y0 + ry;
      if (y < 0 || y >= H) continue;            // uniform branch
      // one base address for the whole row; positions use immediate offsets
      const uint32_t* rowp = act + zero + (((size_t)n * H + y) * W + x0) * CW + pass * CWP;
      uint32_t buf[(PC + 2) * CWP];
#pragma unroll
      for (int cc = -1; cc <= PC; ++cc) {       // batched loads
        const int x = x0 + cc;
        if (x < 0 || x >= W) continue;          // uniform branch
#pragma unroll
        for (int q = 0; q < CWP / 4; ++q)
          *(uint4*)&buf[(cc + 1) * CWP + q * 4] =
              *(const uint4*)(rowp + cc * CW + q * 4);
      }
#pragma unroll
      for (int cc = -1; cc <= PC; ++cc) {       // compute from registers
        const int x = x0 + cc;
        if (x < 0 || x >= W) continue;          // uniform branch
#pragma unroll
        for (int r = 0; r < R; ++r) {
          const int kh = ry - r + 1;            // compile-time after unroll
          if (kh < 0 || kh > 2) continue;
#pragma unroll
          for (int kw = 0; kw < 3; ++kw) {
            const int pxo = cc - kw + 1;        // compile-time
            if (pxo < 0 || pxo >= PC) continue;
#pragma unroll
            for (int cw = 0; cw < CWP; ++cw)
              acc[r * PC + pxo] +=
                  __popc(buf[(cc + 1) * CWP + cw] ^ wreg[(kh * 3 + kw) * CWP + cw]);
          }
        }
      }
    }
  }

  const double sd = (double)bs[ocg * 64 + lane];
  const double td = (double)bt[ocg * 64 + lane];
  if (!POOL) {
    uint64_t bal[R * PC];
#pragma unroll
    for (int r = 0; r < R; ++r)
#pragma unroll
      for (int pxo = 0; pxo < PC; ++pxo) {
        const int y = y0 + r, x = x0 + pxo;
        const int nv = CW * (3 - (y == 0) - (y == H - 1)) * (3 - (x == 0) - (x == W - 1));
        double v = (double)(32 * nv - 2 * acc[r * PC + pxo]) * sd + td;
        bal[r * PC + pxo] = __ballot(v >= 0.0);
      }
    if (lane == 0) {
#pragma unroll
      for (int r = 0; r < R; ++r)
#pragma unroll
        for (int pxo = 0; pxo < PC; ++pxo)
          *(uint64_t*)(out + ((n * H + (y0 + r)) * W + (x0 + pxo)) * OCW + ocg * 2) =
              bal[r * PC + pxo];
    }
  } else {
    static_assert(!POOL || R == 2, "pool needs row pairs");
    uint64_t pooled[PC / 2];
#pragma unroll
    for (int c2 = 0; c2 < PC / 2; ++c2) pooled[c2] = 0;
#pragma unroll
    for (int r = 0; r < R; ++r)
#pragma unroll
      for (int pxo = 0; pxo < PC; ++pxo) {
        const int y = y0 + r, x = x0 + pxo;
        const int nv = CW * (3 - (y == 0) - (y == H - 1)) * (3 - (x == 0) - (x == W - 1));
        double v = (double)(32 * nv - 2 * acc[r * PC + pxo]) * sd + td;
        pooled[pxo >> 1] |= __ballot(v >= 0.0);
      }
    if (lane == 0) {
#pragma unroll
      for (int c2 = 0; c2 < PC / 2; ++c2) {
        const int yo = y0 >> 1, xo = (x0 >> 1) + c2;
        *(uint64_t*)(out + ((n * (H / 2) + yo) * (W / 2) + xo) * OCW + ocg * 2) =
            pooled[c2];
      }
    }
  }
}

// ---------------------------------------------------------------------------
// Conv7 (4x4 VALID, K=512*16=8192 = 256 words) + bn7 + log_softmax (double)
// One block (1 wave) per image.
// ---------------------------------------------------------------------------
__global__ __launch_bounds__(64) void conv7_kernel(
    const uint32_t* __restrict__ act, const uint32_t* __restrict__ wp,
    const float* __restrict__ bs, const float* __restrict__ bt,
    float* __restrict__ out) {
  int n = blockIdx.x;
  int lane = threadIdx.x;
  const uint32_t* a = act + n * 256;
  __shared__ double logits[10];
  for (int o = 0; o < 10; ++o) {
    int acc = 0;
    for (int w = lane; w < 256; w += 64) acc += __popc(a[w] ^ wp[o * 256 + w]);
    for (int off = 32; off > 0; off >>= 1) acc += __shfl_down(acc, off, 64);
    if (lane == 0) {
      double dotd = (double)(8192 - 2 * acc);
      logits[o] = dotd * (double)bs[o] + (double)bt[o];
    }
  }
  __syncthreads();
  if (lane == 0) {
    double m = logits[0];
    for (int o = 1; o < 10; ++o) m = fmax(m, logits[o]);
    double s = 0.0;
    for (int o = 0; o < 10; ++o) s += exp(logits[o] - m);
    double lse = log(s);
    for (int o = 0; o < 10; ++o) out[n * 10 + o] = (float)(logits[o] - m - lse);
  }
}

// ---------------------------------------------------------------------------
extern "C" void kernel_launch(void* const* d_in, const int* in_sizes, int n_in,
                              void* d_out, int out_size, void* d_ws, size_t ws_size,
                              hipStream_t stream) {
  const float* x  = (const float*)d_in[0];
  const float* w1 = (const float*)d_in[1];
  const float* w2 = (const float*)d_in[2];
  const float* w3 = (const float*)d_in[3];
  const float* w4 = (const float*)d_in[4];
  const float* w5 = (const float*)d_in[5];
  const float* w6 = (const float*)d_in[6];
  const float* w7 = (const float*)d_in[7];
  const float* s1 = (const float*)d_in[8];  const float* t1 = (const float*)d_in[9];
  const float* s2 = (const float*)d_in[10]; const float* t2 = (const float*)d_in[11];
  const float* s3 = (const float*)d_in[12]; const float* t3 = (const float*)d_in[13];
  const float* s4 = (const float*)d_in[14]; const float* t4 = (const float*)d_in[15];
  const float* s5 = (const float*)d_in[16]; const float* t5 = (const float*)d_in[17];
  const float* s6 = (const float*)d_in[18]; const float* t6 = (const float*)d_in[19];
  const float* s7 = (const float*)d_in[20]; const float* t7 = (const float*)d_in[21];
  float* out = (float*)d_out;

  uint32_t* ws = (uint32_t*)d_ws;
  uint32_t* A   = ws;                 // 524288 words (2 MB) ping
  uint32_t* B   = ws + 524288;        // 524288 words pong
  uint32_t* wp2 = ws + 1048576;       // 2*9*4*64   = 4608
  uint32_t* wp3 = wp2 + 4608;         // 4*9*4*64   = 9216
  uint32_t* wp4 = wp3 + 9216;         // 4*9*8*64   = 18432
  uint32_t* wp5 = wp4 + 18432;        // 8*9*8*64   = 36864
  uint32_t* wp6 = wp5 + 36864;        // 8*9*16*64  = 73728
  uint32_t* wp7 = wp6 + 73728;        // 10*16*16   = 2560
  uint32_t* wp1 = wp7 + 2560;         // 4*27       = 108

  // pack all weights in one dispatch (ws re-poisoned every call -> repack)
  pack_all_kernel<<<dim3(569), dim3(256), 0, stream>>>(
      w1, w2, w3, w4, w5, w6, w7, wp1, wp2, wp3, wp4, wp5, wp6, wp7);

  // L1: conv1 pixel-per-lane -> A [128,32,32,4]
  conv1_kernel<<<dim3(512, 2), dim3(256), 0, stream>>>(x, wp1, s1, t1, A);

  // L2: bconv+pool (CW=4, 32x32) A->B [128,16,16,4]
  bconv_kernel<4, 4, 32, 32, 8, 2, true>
      <<<dim3(8192, 2), dim3(64), 0, stream>>>(A, wp2, s2, t2, B, 4);

  // L3: bconv (CW=4, 16x16, OC=256) B->A [128,16,16,8]
  bconv_kernel<4, 4, 16, 16, 8, 1, false>
      <<<dim3(4096, 4), dim3(64), 0, stream>>>(B, wp3, s3, t3, A, 8);

  // L4: bconv+pool (CW=8 in 2 passes of 4) A->B [128,8,8,8]
  bconv_kernel<8, 4, 16, 16, 8, 2, true>
      <<<dim3(2048, 4), dim3(64), 0, stream>>>(A, wp4, s4, t4, B, 8);

  // L5: bconv (CW=8 in 2 passes of 4, 8x8, OC=512) B->A [128,8,8,16]
  bconv_kernel<8, 4, 8, 8, 8, 2, false>
      <<<dim3(512, 8), dim3(64), 0, stream>>>(B, wp5, s5, t5, A, 16);

  // L6: bconv+pool (CW=16 in 4 passes of 4) A->B [128,4,4,16]
  bconv_kernel<16, 4, 8, 8, 8, 2, true>
      <<<dim3(512, 8), dim3(64), 0, stream>>>(A, wp6, s6, t6, B, 16);

  // L7: conv7 + bn7 + log_softmax -> out [128,10]
  conv7_kernel<<<dim3(128), dim3(64), 0, stream>>>(B, wp7, s7, t7, out);
}

// Round 9
// 318.646 us; speedup vs baseline: 1.2847x; 1.0114x over previous
//
#include <hip/hip_runtime.h>
#include <cstdint>
#include <math.h>

#define NB 128  // batch size

// ---------------------------------------------------------------------------
// Weight packing + integer bn thresholds.
// Layers 2-6: wp[ocg][tap][cw][oc64] (oc64 = lane).
// Layer 7:    wp[o][tap][cw].
// Layer 1:    wp1[ocw*27 + t] : bit b = (w1[ocw*32+b][tap t] >= 0).
// thr[j] (j = global oc over layers 2..6): min integer d with
//   fl64(d*s + t) >= 0  (d*s exact since d<2^14, s has 24-bit mantissa;
//   fl64 monotone in d) -> bn sign decision == (dot >= thr), bit-identical
//   to the f64 reference.
// ---------------------------------------------------------------------------
__global__ void pack_all_kernel(
    const float* __restrict__ w1,
    const float* __restrict__ w2, const float* __restrict__ w3,
    const float* __restrict__ w4, const float* __restrict__ w5,
    const float* __restrict__ w6, const float* __restrict__ w7,
    const float* __restrict__ s2, const float* __restrict__ t2,
    const float* __restrict__ s3, const float* __restrict__ t3,
    const float* __restrict__ s4, const float* __restrict__ t4,
    const float* __restrict__ s5, const float* __restrict__ t5,
    const float* __restrict__ s6, const float* __restrict__ t6,
    uint32_t* __restrict__ wp1,
    uint32_t* __restrict__ wp2, uint32_t* __restrict__ wp3,
    uint32_t* __restrict__ wp4, uint32_t* __restrict__ wp5,
    uint32_t* __restrict__ wp6, uint32_t* __restrict__ wp7,
    int* __restrict__ thr) {
  int i = blockIdx.x * 256 + threadIdx.x;
  if (i >= 147180) return;
  if (i >= 145516) {  // integer thresholds for layers 2..6
    int j = i - 145516;  // 0..1663
    const float *bsp, *btp; int idx;
    if (j < 128)       { bsp = s2; btp = t2; idx = j; }
    else if (j < 384)  { bsp = s3; btp = t3; idx = j - 128; }
    else if (j < 640)  { bsp = s4; btp = t4; idx = j - 384; }
    else if (j < 1152) { bsp = s5; btp = t5; idx = j - 640; }
    else               { bsp = s6; btp = t6; idx = j - 1152; }
    const double s = (double)bsp[idx], t = (double)btp[idx];
    int d0 = (int)floor(-t / s);
    int th = d0 + 4;
    for (int d = d0 - 3; d <= d0 + 4; ++d)
      if ((double)d * s + t >= 0.0) { th = d; break; }
    thr[j] = th;
    return;
  }
  if (i >= 145408) {  // conv1 sign masks
    int j = i - 145408;          // 0..107
    int ocw = j / 27, t = j % 27;
    uint32_t word = 0;
    for (int b = 0; b < 32; ++b)
      word |= ((w1[(ocw * 32 + b) * 27 + t] >= 0.0f) ? 1u : 0u) << b;
    wp1[ocw * 27 + t] = word;
    return;
  }
  const float* w; uint32_t* wp; int C, KHW; bool nl = true;
  if (i < 4608)        { w = w2; wp = wp2; C = 128; KHW = 9; }
  else if (i < 13824)  { i -= 4608;   w = w3; wp = wp3; C = 128; KHW = 9; }
  else if (i < 32256)  { i -= 13824;  w = w4; wp = wp4; C = 256; KHW = 9; }
  else if (i < 69120)  { i -= 32256;  w = w5; wp = wp5; C = 256; KHW = 9; }
  else if (i < 142848) { i -= 69120;  w = w6; wp = wp6; C = 512; KHW = 9; }
  else                 { i -= 142848; w = w7; wp = wp7; C = 512; KHW = 16; nl = false; }
  int Cw = C >> 5;
  int cw = i % Cw;
  int rest = i / Cw;
  int t = rest % KHW;
  int o = rest / KHW;
  uint32_t word = 0;
  for (int b = 0; b < 32; ++b)
    word |= ((w[(o * C + cw * 32 + b) * KHW + t] >= 0.0f) ? 1u : 0u) << b;
  if (nl) wp[(((o >> 6) * KHW + t) * Cw + cw) * 64 + (o & 63)] = word;
  else    wp[(o * KHW + t) * Cw + cw] = word;
}

// A zero the compiler must treat as divergent (bconv act base addr -> VMEM).
__device__ __forceinline__ int v_zero() {
  return __builtin_amdgcn_ds_bpermute(0, 0);
}

// ---------------------------------------------------------------------------
// Conv1 — pixel-per-lane (unchanged from R8, passing). Each thread owns one
// pixel; 27-tap fp32 window in VGPRs; weight signs = 27 uniform SGPR masks;
// f32 fmac + sound-threshold (1e-3*s) f64 fixup -> f64-exact sign decisions.
// ---------------------------------------------------------------------------
__global__ __launch_bounds__(256, 2) void conv1_kernel(
    const float* __restrict__ x, const uint32_t* __restrict__ wp1,
    const float* __restrict__ bs, const float* __restrict__ bt,
    uint32_t* __restrict__ out) {
  const int tid = blockIdx.x * 256 + threadIdx.x;  // pixel id (exact grid)
  const int og = blockIdx.y;                       // 64-oc group
  const int px = tid & 31, py = (tid >> 5) & 31, n = tid >> 10;

  float xv[27];
#pragma unroll
  for (int ic = 0; ic < 3; ++ic)
#pragma unroll
    for (int kh = 0; kh < 3; ++kh) {
      const int yy = py + kh - 1;
      const int yc = min(max(yy, 0), 31);
      const float* row = x + ((n * 3 + ic) * 32 + yc) * 32;
#pragma unroll
      for (int kw = 0; kw < 3; ++kw) {
        const int xx = px + kw - 1;
        const int xc = min(max(xx, 0), 31);
        const float v = row[xc];
        const bool ok = ((unsigned)yy < 32u) && ((unsigned)xx < 32u);
        xv[ic * 9 + kh * 3 + kw] = ok ? v : 0.0f;
      }
    }

  uint32_t wout[2];
#pragma unroll
  for (int h = 0; h < 2; ++h) {
    const int ocw = og * 2 + h;
    uint32_t m[27];
#pragma unroll
    for (int t = 0; t < 27; ++t) m[t] = wp1[ocw * 27 + t];  // uniform -> SGPR
    uint32_t word = 0;
#pragma unroll
    for (int b = 0; b < 32; b += 4) {  // 4-way ILP on the fmac chains
      float a0 = 0.f, a1 = 0.f, a2 = 0.f, a3 = 0.f;
#pragma unroll
      for (int t = 0; t < 27; ++t) {
        const uint32_t mt = m[t];
        a0 = fmaf(xv[t], ((mt >> (b + 0)) & 1u) ? 1.0f : -1.0f, a0);
        a1 = fmaf(xv[t], ((mt >> (b + 1)) & 1u) ? 1.0f : -1.0f, a1);
        a2 = fmaf(xv[t], ((mt >> (b + 2)) & 1u) ? 1.0f : -1.0f, a2);
        a3 = fmaf(xv[t], ((mt >> (b + 3)) & 1u) ? 1.0f : -1.0f, a3);
      }
      float aa[4] = {a0, a1, a2, a3};
#pragma unroll
      for (int j = 0; j < 4; ++j) {
        const int oc = ocw * 32 + b + j;
        const float s = bs[oc], t0 = bt[oc];        // uniform scalars
        const float v = fmaf(aa[j], s, t0);
        bool pos = v >= 0.0f;
        if (fabsf(v) < 1e-3f * s) {                 // rare exact path
          double ad = 0.0;
          for (int t = 0; t < 27; ++t)
            ad += ((m[t] >> (b + j)) & 1u) ? (double)xv[t] : -(double)xv[t];
          pos = (ad * (double)s + (double)t0) >= 0.0;
        }
        word |= (pos ? 1u : 0u) << (b + j);
      }
    }
    wout[h] = word;
  }
  *(uint64_t*)(out + tid * 4 + og * 2) = ((uint64_t)wout[1] << 32) | wout[0];
}

// ---------------------------------------------------------------------------
// Binary conv 3x3 pad=1 — oc-in-lane, weight-stationary, row-batched loads,
// INTEGER-threshold epilogue, hard 128-reg budget (launch_bounds(64,4)):
// wreg 36 + buf 24 + acc 8 + misc fits in VGPRs -> no AGPR shuffling.
//   lane = oc in the wave's 64-oc group (blockIdx.y); 1 wave = 2 x 4 pixels.
// Inner op: v_xor + accumulating v_bcnt (2 instr / 32 MACs).
// Sign bit: acc <= (32*nv - thr) >> 1  (thr precomputed, f64-exact).
// POOL: OR of the 2x2 ballots.
// ---------------------------------------------------------------------------
template <int CW, int CWP, int H, int W, int PC, int R, bool POOL>
__global__ __launch_bounds__(64, 4) void bconv_kernel(
    const uint32_t* __restrict__ act, const uint32_t* __restrict__ wpk,
    const int* __restrict__ thrp,
    uint32_t* __restrict__ out, int OCW) {
  static_assert(CW % CWP == 0 && CWP % 4 == 0, "");
  const int lane = threadIdx.x;
  const int ocg = blockIdx.y;
  const int zero = v_zero();
  const int cpr = W / PC;
  const int c = blockIdx.x;
  const int cg = c % cpr;
  const int rg = (c / cpr) % (H / R);
  const int n  = c / (cpr * (H / R));
  const int y0 = rg * R, x0 = cg * PC;

  const int thr = thrp[ocg * 64 + lane];

  int acc[R * PC];
#pragma unroll
  for (int p = 0; p < R * PC; ++p) acc[p] = 0;

#pragma unroll
  for (int pass = 0; pass < CW / CWP; ++pass) {
    uint32_t wreg[9 * CWP];
#pragma unroll
    for (int t = 0; t < 9; ++t)
#pragma unroll
      for (int cw = 0; cw < CWP; ++cw)
        wreg[t * CWP + cw] = wpk[(((ocg * 9) + t) * CW + pass * CWP + cw) * 64 + lane];

#pragma unroll
    for (int ry = -1; ry <= R; ++ry) {
      const int y = y0 + ry;
      if (y < 0 || y >= H) continue;            // uniform branch
      const uint32_t* rowp = act + zero + (((size_t)n * H + y) * W + x0) * CW + pass * CWP;
      uint32_t buf[(PC + 2) * CWP];
#pragma unroll
      for (int cc = -1; cc <= PC; ++cc) {       // batched loads, imm offsets
        const int x = x0 + cc;
        if (x < 0 || x >= W) continue;          // uniform branch
#pragma unroll
        for (int q = 0; q < CWP / 4; ++q)
          *(uint4*)&buf[(cc + 1) * CWP + q * 4] =
              *(const uint4*)(rowp + cc * CW + q * 4);
      }
#pragma unroll
      for (int cc = -1; cc <= PC; ++cc) {       // compute from registers
        const int x = x0 + cc;
        if (x < 0 || x >= W) continue;          // uniform branch
#pragma unroll
        for (int r = 0; r < R; ++r) {
          const int kh = ry - r + 1;            // compile-time after unroll
          if (kh < 0 || kh > 2) continue;
#pragma unroll
          for (int kw = 0; kw < 3; ++kw) {
            const int pxo = cc - kw + 1;        // compile-time
            if (pxo < 0 || pxo >= PC) continue;
#pragma unroll
            for (int cw = 0; cw < CWP; ++cw)
              acc[r * PC + pxo] +=
                  __popc(buf[(cc + 1) * CWP + cw] ^ wreg[(kh * 3 + kw) * CWP + cw]);
          }
        }
      }
    }
  }

  if (!POOL) {
    uint64_t bal[R * PC];
#pragma unroll
    for (int r = 0; r < R; ++r)
#pragma unroll
      for (int pxo = 0; pxo < PC; ++pxo) {
        const int y = y0 + r, x = x0 + pxo;
        const int nv32 =
            32 * CW * (3 - (y == 0) - (y == H - 1)) * (3 - (x == 0) - (x == W - 1));
        bal[r * PC + pxo] = __ballot(acc[r * PC + pxo] <= ((nv32 - thr) >> 1));
      }
    if (lane == 0) {
#pragma unroll
      for (int r = 0; r < R; ++r)
#pragma unroll
        for (int pxo = 0; pxo < PC; ++pxo)
          *(uint64_t*)(out + ((n * H + (y0 + r)) * W + (x0 + pxo)) * OCW + ocg * 2) =
              bal[r * PC + pxo];
    }
  } else {
    static_assert(!POOL || R == 2, "pool needs row pairs");
    uint64_t pooled[PC / 2];
#pragma unroll
    for (int c2 = 0; c2 < PC / 2; ++c2) pooled[c2] = 0;
#pragma unroll
    for (int r = 0; r < R; ++r)
#pragma unroll
      for (int pxo = 0; pxo < PC; ++pxo) {
        const int y = y0 + r, x = x0 + pxo;
        const int nv32 =
            32 * CW * (3 - (y == 0) - (y == H - 1)) * (3 - (x == 0) - (x == W - 1));
        pooled[pxo >> 1] |= __ballot(acc[r * PC + pxo] <= ((nv32 - thr) >> 1));
      }
    if (lane == 0) {
#pragma unroll
      for (int c2 = 0; c2 < PC / 2; ++c2) {
        const int yo = y0 >> 1, xo = (x0 >> 1) + c2;
        *(uint64_t*)(out + ((n * (H / 2) + yo) * (W / 2) + xo) * OCW + ocg * 2) =
            pooled[c2];
      }
    }
  }
}

// ---------------------------------------------------------------------------
// Conv7 (4x4 VALID, K=512*16=8192 = 256 words) + bn7 + log_softmax (double)
// One block (1 wave) per image.
// ---------------------------------------------------------------------------
__global__ __launch_bounds__(64) void conv7_kernel(
    const uint32_t* __restrict__ act, const uint32_t* __restrict__ wp,
    const float* __restrict__ bs, const float* __restrict__ bt,
    float* __restrict__ out) {
  int n = blockIdx.x;
  int lane = threadIdx.x;
  const uint32_t* a = act + n * 256;
  __shared__ double logits[10];
  for (int o = 0; o < 10; ++o) {
    int acc = 0;
    for (int w = lane; w < 256; w += 64) acc += __popc(a[w] ^ wp[o * 256 + w]);
    for (int off = 32; off > 0; off >>= 1) acc += __shfl_down(acc, off, 64);
    if (lane == 0) {
      double dotd = (double)(8192 - 2 * acc);
      logits[o] = dotd * (double)bs[o] + (double)bt[o];
    }
  }
  __syncthreads();
  if (lane == 0) {
    double m = logits[0];
    for (int o = 1; o < 10; ++o) m = fmax(m, logits[o]);
    double s = 0.0;
    for (int o = 0; o < 10; ++o) s += exp(logits[o] - m);
    double lse = log(s);
    for (int o = 0; o < 10; ++o) out[n * 10 + o] = (float)(logits[o] - m - lse);
  }
}

// ---------------------------------------------------------------------------
extern "C" void kernel_launch(void* const* d_in, const int* in_sizes, int n_in,
                              void* d_out, int out_size, void* d_ws, size_t ws_size,
                              hipStream_t stream) {
  const float* x  = (const float*)d_in[0];
  const float* w1 = (const float*)d_in[1];
  const float* w2 = (const float*)d_in[2];
  const float* w3 = (const float*)d_in[3];
  const float* w4 = (const float*)d_in[4];
  const float* w5 = (const float*)d_in[5];
  const float* w6 = (const float*)d_in[6];
  const float* w7 = (const float*)d_in[7];
  const float* s1 = (const float*)d_in[8];  const float* t1 = (const float*)d_in[9];
  const float* s2 = (const float*)d_in[10]; const float* t2 = (const float*)d_in[11];
  const float* s3 = (const float*)d_in[12]; const float* t3 = (const float*)d_in[13];
  const float* s4 = (const float*)d_in[14]; const float* t4 = (const float*)d_in[15];
  const float* s5 = (const float*)d_in[16]; const float* t5 = (const float*)d_in[17];
  const float* s6 = (const float*)d_in[18]; const float* t6 = (const float*)d_in[19];
  const float* s7 = (const float*)d_in[20]; const float* t7 = (const float*)d_in[21];
  float* out = (float*)d_out;

  uint32_t* ws = (uint32_t*)d_ws;
  uint32_t* A   = ws;                 // 524288 words (2 MB) ping
  uint32_t* B   = ws + 524288;        // 524288 words pong
  uint32_t* wp2 = ws + 1048576;       // 2*9*4*64   = 4608
  uint32_t* wp3 = wp2 + 4608;         // 4*9*4*64   = 9216
  uint32_t* wp4 = wp3 + 9216;         // 4*9*8*64   = 18432
  uint32_t* wp5 = wp4 + 18432;        // 8*9*8*64   = 36864
  uint32_t* wp6 = wp5 + 36864;        // 8*9*16*64  = 73728
  uint32_t* wp7 = wp6 + 73728;        // 10*16*16   = 2560
  uint32_t* wp1 = wp7 + 2560;         // 4*27       = 108
  int* thr      = (int*)(wp1 + 108);  // 1664 ints: L2@0 L3@128 L4@384 L5@640 L6@1152

  // pack all weights + thresholds in one dispatch (ws re-poisoned -> repack)
  pack_all_kernel<<<dim3(575), dim3(256), 0, stream>>>(
      w1, w2, w3, w4, w5, w6, w7,
      s2, t2, s3, t3, s4, t4, s5, t5, s6, t6,
      wp1, wp2, wp3, wp4, wp5, wp6, wp7, thr);

  // L1: conv1 pixel-per-lane -> A [128,32,32,4]
  conv1_kernel<<<dim3(512, 2), dim3(256), 0, stream>>>(x, wp1, s1, t1, A);

  // L2: bconv+pool (CW=4, 32x32) A->B [128,16,16,4]
  bconv_kernel<4, 4, 32, 32, 4, 2, true>
      <<<dim3(16384, 2), dim3(64), 0, stream>>>(A, wp2, thr + 0, B, 4);

  // L3: bconv (CW=4, 16x16, OC=256) B->A [128,16,16,8]
  bconv_kernel<4, 4, 16, 16, 4, 2, false>
      <<<dim3(4096, 4), dim3(64), 0, stream>>>(B, wp3, thr + 128, A, 8);

  // L4: bconv+pool (CW=8 in 2 passes of 4) A->B [128,8,8,8]
  bconv_kernel<8, 4, 16, 16, 4, 2, true>
      <<<dim3(4096, 4), dim3(64), 0, stream>>>(A, wp4, thr + 384, B, 8);

  // L5: bconv (CW=8 in 2 passes of 4, 8x8, OC=512) B->A [128,8,8,16]
  bconv_kernel<8, 4, 8, 8, 4, 2, false>
      <<<dim3(1024, 8), dim3(64), 0, stream>>>(B, wp5, thr + 640, A, 16);

  // L6: bconv+pool (CW=16 in 4 passes of 4) A->B [128,4,4,16]
  bconv_kernel<16, 4, 8, 8, 4, 2, true>
      <<<dim3(1024, 8), dim3(64), 0, stream>>>(A, wp6, thr + 1152, B, 16);

  // L7: conv7 + bn7 + log_softmax -> out [128,10]
  conv7_kernel<<<dim3(128), dim3(64), 0, stream>>>(B, wp7, s7, t7, out);
}